// Round 15
// baseline (37.346 us; speedup 1.0000x reference)
//
#include <hip/hip_runtime.h>
#include <cstdint>

static constexpr int Bc = 32, Tc = 128, Fc = 32, Hc = 4, HDc = 16, RKc = 16;
static constexpr int Nc = Tc * Fc;  // 4096
static constexpr int WS36 = 36;     // padded [*][32] stride
static constexpr int XLS = 33;      // padded x-row stride in proj

__device__ __forceinline__ uint32_t rotl32(uint32_t v, int r) {
  return (v << r) | (v >> (32 - r));
}

__device__ __forceinline__ void threefry2x32(uint32_t k0, uint32_t k1,
                                             uint32_t& x0, uint32_t& x1) {
  uint32_t k2 = k0 ^ k1 ^ 0x1BD11BDAu;
  x0 += k0; x1 += k1;
#define TF_R(r) { x0 += x1; x1 = rotl32(x1, (r)); x1 ^= x0; }
  TF_R(13) TF_R(15) TF_R(26) TF_R(6)
  x0 += k1; x1 += k2 + 1u;
  TF_R(17) TF_R(29) TF_R(16) TF_R(24)
  x0 += k2; x1 += k0 + 2u;
  TF_R(13) TF_R(15) TF_R(26) TF_R(6)
  x0 += k0; x1 += k1 + 3u;
  TF_R(17) TF_R(29) TF_R(16) TF_R(24)
  x0 += k1; x1 += k2 + 4u;
  TF_R(13) TF_R(15) TF_R(26) TF_R(6)
  x0 += k2; x1 += k0 + 5u;
#undef TF_R
}

__device__ __forceinline__ float erfinv_f32(float x) {
  float w = -__logf((1.0f - x) * (1.0f + x));
  float p;
  if (w < 5.0f) {
    w -= 2.5f;
    p = 2.81022636e-08f;
    p = fmaf(p, w, 3.43273939e-07f);
    p = fmaf(p, w, -3.5233877e-06f);
    p = fmaf(p, w, -4.39150654e-06f);
    p = fmaf(p, w, 0.00021858087f);
    p = fmaf(p, w, -0.00125372503f);
    p = fmaf(p, w, -0.00417768164f);
    p = fmaf(p, w, 0.246640727f);
    p = fmaf(p, w, 1.50140941f);
  } else {
    w = sqrtf(w) - 3.0f;
    p = -0.000200214257f;
    p = fmaf(p, w, 0.000100950558f);
    p = fmaf(p, w, 0.00134934322f);
    p = fmaf(p, w, -0.00367342844f);
    p = fmaf(p, w, 0.00573950773f);
    p = fmaf(p, w, -0.0076224613f);
    p = fmaf(p, w, 0.00943887047f);
    p = fmaf(p, w, 1.00167406f);
    p = fmaf(p, w, 2.83297682f);
  }
  return p * x;
}

__device__ __forceinline__ float jax_normal_from_bits(uint32_t bits) {
  const float lo = -0.99999994f;
  float f = __uint_as_float((bits >> 9) | 0x3f800000u) - 1.0f;
  float u = fmaxf(lo, f * 2.0f + lo);
  return 1.41421354f * erfinv_f32(u);
}

// ---------------------------------------------------------------------------
// P: q/k projections. grid (b) = 32 blocks, 512 threads (2 waves/SIMD).
// thread = (t = tid&127, h = tid>>7). All LDS reads conflict-free/broadcast.
// ---------------------------------------------------------------------------
__global__ __launch_bounds__(512)
void proj_kernel(const float* __restrict__ x, const float* __restrict__ weight,
                 const float* __restrict__ tqg, const float* __restrict__ tkg,
                 float* __restrict__ ws_q, float* __restrict__ ws_k) {
  const int b = blockIdx.x;
  const int tid = (int)threadIdx.x;
  __shared__ float xL[Tc * XLS];
  __shared__ float wqS[Hc * Fc], wkS[Hc * Fc];

  const float* xb = x + (size_t)b * Nc;
  for (int j = tid; j < Nc / 4; j += 512) {
    int row = j >> 3, c4 = j & 7;
    float4 v = *(const float4*)&xb[row * Fc + 4 * c4];
    xL[row * XLS + 4 * c4 + 0] = v.x;
    xL[row * XLS + 4 * c4 + 1] = v.y;
    xL[row * XLS + 4 * c4 + 2] = v.z;
    xL[row * XLS + 4 * c4 + 3] = v.w;
  }
  if (tid < Hc * Fc) {
    int h = tid >> 5, f = tid & 31;
    const float* W0 = weight + h * (Fc * HDc) + f * HDc;
    float aq = 0.f, ak = 0.f;
    for (int d = 0; d < HDc; ++d) {
      aq += W0[d] * tqg[h * HDc + d];
      ak += W0[d] * tkg[h * HDc + d];
    }
    wqS[tid] = aq; wkS[tid] = ak;
  }
  __syncthreads();

  const int t = tid & 127, h = tid >> 7;  // h wave-uniform
  float aq = 0.f, ak = 0.f;
  for (int f = 0; f < Fc; ++f) {
    float xv = xL[t * XLS + f];           // (t+f)%32 conflict-free
    aq += xv * wqS[h * Fc + f];           // broadcast
    ak += xv * wkS[h * Fc + f];
  }
  ws_q[h * Nc + b * Tc + t] = aq;
  ws_k[h * Nc + b * Tc + t] = ak;
}

// ---------------------------------------------------------------------------
// S: scores + softmax + threshold -> ta + rs. grid (h, chunk=32 of 4 rows),
// 256 threads. (R14 verbatim — proven.)
// ---------------------------------------------------------------------------
__global__ __launch_bounds__(256)
void score_kernel(const float* __restrict__ ws_q, const float* __restrict__ ws_k,
                  float* __restrict__ ws_ta, float* __restrict__ ws_rs) {
  const int h = blockIdx.x, chunk = blockIdx.y;
  const int tid = (int)threadIdx.x;
  __shared__ float kS[Bc * Tc];
  __shared__ float qS[Bc * 4];

  for (int j = tid; j < Bc * Tc / 4; j += 256)
    ((float4*)kS)[j] = ((const float4*)(ws_k + (size_t)h * Nc))[j];
  if (tid < Bc * 4) {
    int b = tid >> 2, r = tid & 3;
    qS[tid] = ws_q[(size_t)h * Nc + b * Tc + 4 * chunk + r];
  }
  __syncthreads();

  const int r = tid >> 6, lane = tid & 63;
  const int gr = 4 * chunk + r;
  float acc0 = 0.f, acc1 = 0.f;
  for (int b = 0; b < Bc; ++b) {
    float q = qS[b * 4 + r];
    float k0 = kS[b * Tc + lane];
    float k1 = kS[b * Tc + lane + 64];
    float s0 = q + k0, s1 = q + k1;
    acc0 += fmaxf(s0, 0.2f * s0);
    acc1 += fmaxf(s1, 0.2f * s1);
  }
  acc0 *= (1.0f / 32.0f);
  acc1 *= (1.0f / 32.0f);

  float m = fmaxf(acc0, acc1);
  for (int o = 32; o > 0; o >>= 1) m = fmaxf(m, __shfl_xor(m, o, 64));
  float e0 = expf(acc0 - m), e1 = expf(acc1 - m);
  float se = e0 + e1;
  for (int o = 32; o > 0; o >>= 1) se += __shfl_xor(se, o, 64);
  float p0 = e0 / se, p1 = e1 / se;
  p0 = ((p0 > 0.01f) && (lane != gr)) ? p0 : 0.f;
  p1 = ((p1 > 0.01f) && (lane + 64 != gr)) ? p1 : 0.f;
  float rs = p0 + p1;
  for (int o = 32; o > 0; o >>= 1) rs += __shfl_xor(rs, o, 64);

  float* tar = ws_ta + (size_t)h * (Tc * Tc) + (size_t)gr * Tc;
  tar[lane] = p0;
  tar[lane + 64] = p1;
  if (lane == 0) ws_rs[h * Tc + gr] = rs;
}

// ---------------------------------------------------------------------------
// H: per-head fa + PRNG v0 + power iteration -> sn. grid (h) = 4 blocks,
// 512 threads. Register pi (R13-proven), fa -> ws for conv.
// ---------------------------------------------------------------------------
__global__ __launch_bounds__(512, 1)
void head_kernel(const float* __restrict__ ffg, const float* __restrict__ ws_ta,
                 const float* __restrict__ ws_rs, float* __restrict__ ws_fa,
                 float* __restrict__ ws_rsF, float* __restrict__ ws_sn) {
  const int h = blockIdx.x;
  const int tid = (int)threadIdx.x;
  const int lane = tid & 63, wvi = tid >> 6;

  __shared__ __align__(16) float faTS[Fc * WS36];  // faT[f2][f1]
  __shared__ __align__(16) float vtmp[Nc];
  __shared__ __align__(16) float wbuf[Tc * WS36];
  __shared__ float rsT[Tc], rsF[Fc];
  __shared__ float red[8][2];
  __shared__ int flagS;

  const int t = tid >> 2, fq = tid & 3, f0 = 8 * fq;

  if (tid < Tc) rsT[tid] = ws_rs[h * Tc + tid];
  if (tid < 64) {
    int nz = (ws_rs[h * Tc + tid] > 0.f) || (ws_rs[h * Tc + tid + 64] > 0.f);
    unsigned long long bal = __ballot(nz);
    if (tid == 0) flagS = (bal != 0ull) ? 1 : 0;
  }
  // fa = threshold(softmax(leaky_relu(U V^T), axis=1)); 2 cells/thread
  for (int j2 = tid; j2 < Fc * Fc; j2 += 512) {
    const float* U = ffg + h * (2 * Fc * RKc);
    const float* V = U + Fc * RKc;
    int f1 = j2 >> 5, f2 = j2 & 31;
    float acc = 0.f;
    for (int r = 0; r < RKc; ++r) acc += U[f1 * RKc + r] * V[f2 * RKc + r];
    float val = fmaxf(acc, 0.2f * acc);
    float m = val;
    for (int o = 16; o > 0; o >>= 1) m = fmaxf(m, __shfl_xor(m, o, 32));
    float e = expf(val - m), se = e;
    for (int o = 16; o > 0; o >>= 1) se += __shfl_xor(se, o, 32);
    float pv = e / se;
    pv = (pv > 0.01f && f1 != f2) ? pv : 0.f;
    faTS[f2 * WS36 + f1] = pv;
    ws_fa[h * (Fc * Fc) + j2] = pv;   // row-major for conv
    float rsum = pv;
    for (int o = 16; o > 0; o >>= 1) rsum += __shfl_xor(rsum, o, 32);
    if (f2 == 0) { rsF[f1] = rsum; ws_rsF[h * Fc + f1] = rsum; }
  }
  // PRNG: 4 pairs/thread -> vtmp
  {
    uint32_t fk0 = 0u, fk1 = (uint32_t)h;
    threefry2x32(0u, 42u, fk0, fk1);
    float n0[4], n1[4];
#pragma unroll
    for (int jj = 0; jj < 4; ++jj) {
      int l = tid * 4 + jj;
      uint32_t c0 = (uint32_t)l, c1 = (uint32_t)(l + 2048);
      threefry2x32(fk0, fk1, c0, c1);
      n0[jj] = jax_normal_from_bits(c0);
      n1[jj] = jax_normal_from_bits(c1);
    }
    *(float4*)&vtmp[tid * 4]        = make_float4(n0[0], n0[1], n0[2], n0[3]);
    *(float4*)&vtmp[2048 + tid * 4] = make_float4(n1[0], n1[1], n1[2], n1[3]);
  }
  __syncthreads();

  float s_reg[8], v[8];
  {
    float rrow = rsT[t];
#pragma unroll
    for (int j = 0; j < 8; ++j)
      s_reg[j] = 1.0f / sqrtf(rrow + rsF[f0 + j] + 1.0f + 1e-10f);
    float4 v0a = *(const float4*)&vtmp[t * Fc + f0];
    float4 v0b = *(const float4*)&vtmp[t * Fc + f0 + 4];
    v[0]=v0a.x; v[1]=v0a.y; v[2]=v0a.z; v[3]=v0a.w;
    v[4]=v0b.x; v[5]=v0b.y; v[6]=v0b.z; v[7]=v0b.w;
  }

  const int srcBase = lane & 60;
  float u4[8];
  for (int it = 0; it < 4; ++it) {
    float w[8];
#pragma unroll
    for (int j = 0; j < 8; ++j) w[j] = s_reg[j] * v[j];
    if (flagS) {
      *(float4*)&wbuf[t * WS36 + f0]     = make_float4(w[0], w[1], w[2], w[3]);
      *(float4*)&wbuf[t * WS36 + f0 + 4] = make_float4(w[4], w[5], w[6], w[7]);
      __syncthreads();
    }
    float wrow[32];
#pragma unroll
    for (int oq = 0; oq < 4; ++oq)
#pragma unroll
      for (int j = 0; j < 8; ++j)
        wrow[oq * 8 + j] = __shfl(w[j], srcBase + oq, 64);
    float acc[8] = {};
#pragma unroll
    for (int f2 = 0; f2 < Fc; ++f2) {
      float4 fa0 = *(const float4*)&faTS[f2 * WS36 + f0];
      float4 fa1 = *(const float4*)&faTS[f2 * WS36 + f0 + 4];
      float ww = wrow[f2];
      acc[0] += ww * fa0.x; acc[1] += ww * fa0.y;
      acc[2] += ww * fa0.z; acc[3] += ww * fa0.w;
      acc[4] += ww * fa1.x; acc[5] += ww * fa1.y;
      acc[6] += ww * fa1.z; acc[7] += ww * fa1.w;
    }
    if (flagS) {
      const float* taG = ws_ta + (size_t)h * (Tc * Tc) + (size_t)t * Tc;
      for (int k = 0; k < Tc; ++k) {
        float tak = taG[k];
        float4 w0 = *(const float4*)&wbuf[k * WS36 + f0];
        float4 w1 = *(const float4*)&wbuf[k * WS36 + f0 + 4];
        acc[0] += tak * w0.x; acc[1] += tak * w0.y;
        acc[2] += tak * w0.z; acc[3] += tak * w0.w;
        acc[4] += tak * w1.x; acc[5] += tak * w1.y;
        acc[6] += tak * w1.z; acc[7] += tak * w1.w;
      }
      __syncthreads();
    }
    float nv[8];
#pragma unroll
    for (int j = 0; j < 8; ++j) {
      float a = acc[j] + w[j];
      nv[j] = v[j] - s_reg[j] * a;
    }
    if (it < 3) {
#pragma unroll
      for (int j = 0; j < 8; ++j) v[j] = nv[j];
    } else {
#pragma unroll
      for (int j = 0; j < 8; ++j) u4[j] = nv[j];
    }
  }
  {
    float pn = 0.f, pd = 0.f;
#pragma unroll
    for (int j = 0; j < 8; ++j) { pn += v[j] * u4[j]; pd += v[j] * v[j]; }
    for (int o = 32; o > 0; o >>= 1) {
      pn += __shfl_down(pn, o, 64);
      pd += __shfl_down(pd, o, 64);
    }
    if (lane == 0) { red[wvi][0] = pn; red[wvi][1] = pd; }
  }
  __syncthreads();
  if (tid == 0) {
    float num = 0.f, den = 0.f;
    for (int i2 = 0; i2 < 8; ++i2) { num += red[i2][0]; den += red[i2][1]; }
    ws_sn[h] = fmaxf(fabsf(num / den), 1.0f);
  }
}

// ---------------------------------------------------------------------------
// C: conv only. grid (b, h) = 128 blocks, 512 threads, 1 barrier (flag=0).
// thread = (t = tid>>2, fq = tid&3). All per-head inputs from ws.
// ---------------------------------------------------------------------------
__global__ __launch_bounds__(512, 1)
void conv_kernel(const float* __restrict__ x, const float* __restrict__ weight,
                 const float* __restrict__ bias, const float* __restrict__ ws_ta,
                 const float* __restrict__ ws_rs, const float* __restrict__ ws_fa,
                 const float* __restrict__ ws_rsF, const float* __restrict__ ws_sn,
                 float* __restrict__ out) {
  const int b = blockIdx.x, h = blockIdx.y;
  const int tid = (int)threadIdx.x;
  const int lane = tid & 63;

  __shared__ __align__(16) float faS[Fc * WS36];   // fa[f2][f] row-major
  __shared__ __align__(16) float W0s[Fc * HDc];
  __shared__ __align__(16) float W1s[Fc * HDc];
  __shared__ __align__(16) float wbuf[Tc * WS36];  // flag-path Z rows
  __shared__ float rsT[Tc], rsF[Fc];
  __shared__ int flagS;

  const int t = tid >> 2, fq = tid & 3, f0 = 8 * fq;

  if (tid < Tc) rsT[tid] = ws_rs[h * Tc + tid];
  if (tid < Fc) rsF[tid] = ws_rsF[h * Fc + tid];
  {
    W0s[tid] = weight[h * (Fc * HDc) + tid];
    W1s[tid] = weight[(Hc + h) * (Fc * HDc) + tid];
  }
  for (int i = tid; i < Fc * Fc; i += 512)
    faS[(i >> 5) * WS36 + (i & 31)] = ws_fa[h * (Fc * Fc) + i];
  if (tid < 64) {
    int nz = (ws_rs[h * Tc + tid] > 0.f) || (ws_rs[h * Tc + tid + 64] > 0.f);
    unsigned long long bal = __ballot(nz);
    if (tid == 0) flagS = (bal != 0ull) ? 1 : 0;
  }
  const float* xb = x + (size_t)b * Nc;
  float4 xva = *(const float4*)&xb[t * Fc + f0];
  float4 xvb = *(const float4*)&xb[t * Fc + f0 + 4];
  const float sn = ws_sn[h];
  const float csn = 2.0f / sn;
  const float cm1 = csn - 1.0f;
  __syncthreads();  // BARRIER 1 (only one when flag==0)

  float s_reg[8];
  {
    float rrow = rsT[t];
#pragma unroll
    for (int j = 0; j < 8; ++j)
      s_reg[j] = 1.0f / sqrtf(rrow + rsF[f0 + j] + 1.0f + 1e-10f);
  }
  float X[8] = {xva.x, xva.y, xva.z, xva.w, xvb.x, xvb.y, xvb.z, xvb.w};
  float Z[8];
#pragma unroll
  for (int j = 0; j < 8; ++j) Z[j] = s_reg[j] * X[j];

  float gacc[8] = {};
  if (flagS) {  // rare: G1[t][f] = sum_k ta[k][t] Z[k][f]
    *(float4*)&wbuf[t * WS36 + f0]     = make_float4(Z[0], Z[1], Z[2], Z[3]);
    *(float4*)&wbuf[t * WS36 + f0 + 4] = make_float4(Z[4], Z[5], Z[6], Z[7]);
    __syncthreads();
    const float* taG = ws_ta + (size_t)h * (Tc * Tc);
    for (int k = 0; k < Tc; ++k) {
      float tak = taG[(size_t)k * Tc + t];
      float4 z0 = *(const float4*)&wbuf[k * WS36 + f0];
      float4 z1 = *(const float4*)&wbuf[k * WS36 + f0 + 4];
      gacc[0] += tak * z0.x; gacc[1] += tak * z0.y;
      gacc[2] += tak * z0.z; gacc[3] += tak * z0.w;
      gacc[4] += tak * z1.x; gacc[5] += tak * z1.y;
      gacc[6] += tak * z1.z; gacc[7] += tak * z1.w;
    }
  }
  // Z @ fa: sum_f2 Z[t][f2] * fa[f2][f]
  {
    const int srcBase = lane & 60;
    float zrow[32];
#pragma unroll
    for (int oq = 0; oq < 4; ++oq)
#pragma unroll
      for (int j = 0; j < 8; ++j)
        zrow[oq * 8 + j] = __shfl(Z[j], srcBase + oq, 64);
#pragma unroll
    for (int f2 = 0; f2 < Fc; ++f2) {
      float4 fa0 = *(const float4*)&faS[f2 * WS36 + f0];
      float4 fa1 = *(const float4*)&faS[f2 * WS36 + f0 + 4];
      float zz = zrow[f2];
      gacc[0] += zz * fa0.x; gacc[1] += zz * fa0.y;
      gacc[2] += zz * fa0.z; gacc[3] += zz * fa0.w;
      gacc[4] += zz * fa1.x; gacc[5] += zz * fa1.y;
      gacc[6] += zz * fa1.z; gacc[7] += zz * fa1.w;
    }
  }
  float G[8];
#pragma unroll
  for (int j = 0; j < 8; ++j)
    G[j] = cm1 * X[j] - csn * s_reg[j] * (gacc[j] + Z[j]);

  float acc2[16] = {};
#pragma unroll
  for (int jf = 0; jf < 8; ++jf) {
    int f = f0 + jf;
#pragma unroll
    for (int hq = 0; hq < 4; ++hq) {
      float4 w0 = *(const float4*)&W0s[f * HDc + 4 * hq];
      float4 w1 = *(const float4*)&W1s[f * HDc + 4 * hq];
      acc2[4*hq+0] += X[jf] * w0.x + G[jf] * w1.x;
      acc2[4*hq+1] += X[jf] * w0.y + G[jf] * w1.y;
      acc2[4*hq+2] += X[jf] * w0.z + G[jf] * w1.z;
      acc2[4*hq+3] += X[jf] * w0.w + G[jf] * w1.w;
    }
  }
#pragma unroll
  for (int i2 = 0; i2 < 16; ++i2) {
    acc2[i2] += __shfl_xor(acc2[i2], 1, 64);
    acc2[i2] += __shfl_xor(acc2[i2], 2, 64);
  }
  {
    float4 bv = *(const float4*)&bias[h * HDc + 4 * fq];
    float4 o4;
    if      (fq == 0) o4 = make_float4(acc2[0],  acc2[1],  acc2[2],  acc2[3]);
    else if (fq == 1) o4 = make_float4(acc2[4],  acc2[5],  acc2[6],  acc2[7]);
    else if (fq == 2) o4 = make_float4(acc2[8],  acc2[9],  acc2[10], acc2[11]);
    else              o4 = make_float4(acc2[12], acc2[13], acc2[14], acc2[15]);
    o4.x += bv.x; o4.y += bv.y; o4.z += bv.z; o4.w += bv.w;
    *(float4*)&out[((size_t)b * Tc + t) * (Hc * HDc) + h * HDc + 4 * fq] = o4;
  }
}

extern "C" void kernel_launch(void* const* d_in, const int* in_sizes, int n_in,
                              void* d_out, int out_size, void* d_ws, size_t ws_size,
                              hipStream_t stream) {
  const float* x      = (const float*)d_in[0];
  const float* weight = (const float*)d_in[1];
  const float* bias   = (const float*)d_in[2];
  const float* tqg    = (const float*)d_in[3];
  const float* tkg    = (const float*)d_in[4];
  const float* ffg    = (const float*)d_in[5];
  float* out = (float*)d_out;

  float* ws = (float*)d_ws;
  float* ws_ta  = ws;             // 65536
  float* ws_rs  = ws + 65536;     // 512
  float* ws_q   = ws + 66048;     // 16384
  float* ws_k   = ws + 82432;     // 16384
  float* ws_fa  = ws + 98816;     // 4096
  float* ws_rsF = ws + 102912;    // 128
  float* ws_sn  = ws + 103040;    // 4

  proj_kernel<<<dim3(Bc), dim3(512), 0, stream>>>(
      x, weight, tqg, tkg, ws_q, ws_k);
  score_kernel<<<dim3(Hc, 32), dim3(256), 0, stream>>>(
      ws_q, ws_k, ws_ta, ws_rs);
  head_kernel<<<dim3(Hc), dim3(512), 0, stream>>>(
      ffg, ws_ta, ws_rs, ws_fa, ws_rsF, ws_sn);
  conv_kernel<<<dim3(Bc, Hc), dim3(512), 0, stream>>>(
      x, weight, bias, ws_ta, ws_rs, ws_fa, ws_rsF, ws_sn, out);
}

// Round 16
// 28.154 us; speedup vs baseline: 1.3265x; 1.3265x over previous
//
#include <hip/hip_runtime.h>
#include <cstdint>

static constexpr int Bc = 32, Tc = 128, Fc = 32, Hc = 4, HDc = 16, RKc = 16;
static constexpr int Nc = Tc * Fc;  // 4096
static constexpr int WS36 = 36;     // padded [*][32] stride
static constexpr int XLS = 33;      // padded x-row stride in proj

__device__ __forceinline__ uint32_t rotl32(uint32_t v, int r) {
  return (v << r) | (v >> (32 - r));
}

__device__ __forceinline__ void threefry2x32(uint32_t k0, uint32_t k1,
                                             uint32_t& x0, uint32_t& x1) {
  uint32_t k2 = k0 ^ k1 ^ 0x1BD11BDAu;
  x0 += k0; x1 += k1;
#define TF_R(r) { x0 += x1; x1 = rotl32(x1, (r)); x1 ^= x0; }
  TF_R(13) TF_R(15) TF_R(26) TF_R(6)
  x0 += k1; x1 += k2 + 1u;
  TF_R(17) TF_R(29) TF_R(16) TF_R(24)
  x0 += k2; x1 += k0 + 2u;
  TF_R(13) TF_R(15) TF_R(26) TF_R(6)
  x0 += k0; x1 += k1 + 3u;
  TF_R(17) TF_R(29) TF_R(16) TF_R(24)
  x0 += k1; x1 += k2 + 4u;
  TF_R(13) TF_R(15) TF_R(26) TF_R(6)
  x0 += k2; x1 += k0 + 5u;
#undef TF_R
}

__device__ __forceinline__ float erfinv_f32(float x) {
  float w = -__logf((1.0f - x) * (1.0f + x));
  float p;
  if (w < 5.0f) {
    w -= 2.5f;
    p = 2.81022636e-08f;
    p = fmaf(p, w, 3.43273939e-07f);
    p = fmaf(p, w, -3.5233877e-06f);
    p = fmaf(p, w, -4.39150654e-06f);
    p = fmaf(p, w, 0.00021858087f);
    p = fmaf(p, w, -0.00125372503f);
    p = fmaf(p, w, -0.00417768164f);
    p = fmaf(p, w, 0.246640727f);
    p = fmaf(p, w, 1.50140941f);
  } else {
    w = sqrtf(w) - 3.0f;
    p = -0.000200214257f;
    p = fmaf(p, w, 0.000100950558f);
    p = fmaf(p, w, 0.00134934322f);
    p = fmaf(p, w, -0.00367342844f);
    p = fmaf(p, w, 0.00573950773f);
    p = fmaf(p, w, -0.0076224613f);
    p = fmaf(p, w, 0.00943887047f);
    p = fmaf(p, w, 1.00167406f);
    p = fmaf(p, w, 2.83297682f);
  }
  return p * x;
}

__device__ __forceinline__ float jax_normal_from_bits(uint32_t bits) {
  const float lo = -0.99999994f;
  float f = __uint_as_float((bits >> 9) | 0x3f800000u) - 1.0f;
  float u = fmaxf(lo, f * 2.0f + lo);
  return 1.41421354f * erfinv_f32(u);
}

// ---------------------------------------------------------------------------
// P: q/k projections (+ fa for blocks 0..3). grid (b) = 32 blocks, 512 thr.
// ---------------------------------------------------------------------------
__global__ __launch_bounds__(512)
void proj_kernel(const float* __restrict__ x, const float* __restrict__ weight,
                 const float* __restrict__ tqg, const float* __restrict__ tkg,
                 const float* __restrict__ ffg, float* __restrict__ ws_q,
                 float* __restrict__ ws_k, float* __restrict__ ws_fa,
                 float* __restrict__ ws_rsF) {
  const int b = blockIdx.x;
  const int tid = (int)threadIdx.x;
  __shared__ float xL[Tc * XLS];
  __shared__ float wqS[Hc * Fc], wkS[Hc * Fc];

  const float* xb = x + (size_t)b * Nc;
  for (int j = tid; j < Nc / 4; j += 512) {
    int row = j >> 3, c4 = j & 7;
    float4 v = *(const float4*)&xb[row * Fc + 4 * c4];
    xL[row * XLS + 4 * c4 + 0] = v.x;
    xL[row * XLS + 4 * c4 + 1] = v.y;
    xL[row * XLS + 4 * c4 + 2] = v.z;
    xL[row * XLS + 4 * c4 + 3] = v.w;
  }
  if (tid < Hc * Fc) {
    int h = tid >> 5, f = tid & 31;
    const float* W0 = weight + h * (Fc * HDc) + f * HDc;
    float aq = 0.f, ak = 0.f;
    for (int d = 0; d < HDc; ++d) {
      aq += W0[d] * tqg[h * HDc + d];
      ak += W0[d] * tkg[h * HDc + d];
    }
    wqS[tid] = aq; wkS[tid] = ak;
  }
  // fa for head h2 = b (blocks 0..3): independent of LDS above
  if (b < Hc) {
    const int h2 = b;
    for (int j2 = tid; j2 < Fc * Fc; j2 += 512) {
      const float* U = ffg + h2 * (2 * Fc * RKc);
      const float* V = U + Fc * RKc;
      int f1 = j2 >> 5, f2 = j2 & 31;
      float acc = 0.f;
      for (int r = 0; r < RKc; ++r) acc += U[f1 * RKc + r] * V[f2 * RKc + r];
      float val = fmaxf(acc, 0.2f * acc);
      float m = val;
      for (int o = 16; o > 0; o >>= 1) m = fmaxf(m, __shfl_xor(m, o, 32));
      float e = expf(val - m), se = e;
      for (int o = 16; o > 0; o >>= 1) se += __shfl_xor(se, o, 32);
      float pv = e / se;
      pv = (pv > 0.01f && f1 != f2) ? pv : 0.f;
      ws_fa[h2 * (Fc * Fc) + j2] = pv;
      float rsum = pv;
      for (int o = 16; o > 0; o >>= 1) rsum += __shfl_xor(rsum, o, 32);
      if (f2 == 0) ws_rsF[h2 * Fc + f1] = rsum;
    }
  }
  __syncthreads();

  const int t = tid & 127, h = tid >> 7;  // h wave-uniform
  float aq = 0.f, ak = 0.f;
  for (int f = 0; f < Fc; ++f) {
    float xv = xL[t * XLS + f];           // (t+f)%32 conflict-free
    aq += xv * wqS[h * Fc + f];           // broadcast
    ak += xv * wkS[h * Fc + f];
  }
  ws_q[h * Nc + b * Tc + t] = aq;
  ws_k[h * Nc + b * Tc + t] = ak;
}

// ---------------------------------------------------------------------------
// S: scores + softmax + threshold + ROW-LOCAL power iteration partials.
// grid (h, chunk=32 of 4 rows), 256 threads.
// ---------------------------------------------------------------------------
__global__ __launch_bounds__(256)
void score_kernel(const float* __restrict__ ws_q, const float* __restrict__ ws_k,
                  const float* __restrict__ ws_fa, const float* __restrict__ ws_rsF,
                  float* __restrict__ ws_ta, float* __restrict__ ws_rs,
                  float* __restrict__ ws_pn, float* __restrict__ ws_pd) {
  const int h = blockIdx.x, chunk = blockIdx.y;
  const int tid = (int)threadIdx.x;
  __shared__ float kS[Bc * Tc];          // 16 KB
  __shared__ float qS[Bc * 4];
  __shared__ float faTS[Fc * WS36];      // faT[f2][f1]
  __shared__ float rsFl[Fc];
  __shared__ float rsLoc[4];
  __shared__ float redp[4][2];

  for (int j = tid; j < Bc * Tc / 4; j += 256)
    ((float4*)kS)[j] = ((const float4*)(ws_k + (size_t)h * Nc))[j];
  if (tid < Bc * 4) {
    int b = tid >> 2, r = tid & 3;
    qS[tid] = ws_q[(size_t)h * Nc + b * Tc + 4 * chunk + r];
  }
  for (int i = tid; i < Fc * Fc; i += 256) {
    int f1 = i >> 5, f2 = i & 31;
    faTS[f2 * WS36 + f1] = ws_fa[h * (Fc * Fc) + i];
  }
  if (tid < Fc) rsFl[tid] = ws_rsF[h * Fc + tid];
  __syncthreads();

  // ---- scores + softmax + threshold (R14-proven) ----
  const int r = tid >> 6, lane = tid & 63;
  const int gr = 4 * chunk + r;
  float acc0 = 0.f, acc1 = 0.f;
  for (int b = 0; b < Bc; ++b) {
    float q = qS[b * 4 + r];
    float k0 = kS[b * Tc + lane];
    float k1 = kS[b * Tc + lane + 64];
    float s0 = q + k0, s1 = q + k1;
    acc0 += fmaxf(s0, 0.2f * s0);
    acc1 += fmaxf(s1, 0.2f * s1);
  }
  acc0 *= (1.0f / 32.0f);
  acc1 *= (1.0f / 32.0f);
  float m = fmaxf(acc0, acc1);
  for (int o = 32; o > 0; o >>= 1) m = fmaxf(m, __shfl_xor(m, o, 64));
  float e0 = expf(acc0 - m), e1 = expf(acc1 - m);
  float se = e0 + e1;
  for (int o = 32; o > 0; o >>= 1) se += __shfl_xor(se, o, 64);
  float p0 = e0 / se, p1 = e1 / se;
  p0 = ((p0 > 0.01f) && (lane != gr)) ? p0 : 0.f;
  p1 = ((p1 > 0.01f) && (lane + 64 != gr)) ? p1 : 0.f;
  float rs = p0 + p1;
  for (int o = 32; o > 0; o >>= 1) rs += __shfl_xor(rs, o, 64);
  float* tar = ws_ta + (size_t)h * (Tc * Tc) + (size_t)gr * Tc;
  tar[lane] = p0;
  tar[lane + 64] = p1;
  if (lane == 0) { ws_rs[h * Tc + gr] = rs; rsLoc[r] = rs; }
  __syncthreads();

  // ---- row-local pi (valid iff ta==0 everywhere; C checks the flag) ----
  if (tid < 128) {
    const int g = tid >> 5, f = tid & 31;   // row 4*chunk+g, feature f
    const int t = 4 * chunk + g;
    float s = 1.0f / sqrtf(rsLoc[g] + rsFl[f] + 1.0f + 1e-10f);
    float v;
    {
      uint32_t fk0 = 0u, fk1 = (uint32_t)h;
      threefry2x32(0u, 42u, fk0, fk1);
      int l = t * Fc + f;
      int pr = l & 2047;
      uint32_t c0 = (uint32_t)pr, c1 = (uint32_t)(pr + 2048);
      threefry2x32(fk0, fk1, c0, c1);
      v = jax_normal_from_bits(l < 2048 ? c0 : c1);
    }
    float u4v = 0.f;
    for (int it = 0; it < 4; ++it) {
      float w = s * v;
      float acc = 0.f;
#pragma unroll
      for (int f2 = 0; f2 < Fc; ++f2) {
        float ww = __shfl(w, f2, 32);            // row's w[f2]
        acc += faTS[f2 * WS36 + f] * ww;         // fa[f][f2], lane-consecutive
      }
      float nv = v - s * (acc + w);              // (L u)[t,f]
      if (it < 3) v = nv; else u4v = nv;         // v ends as u3
    }
    float pn = v * u4v, pd = v * v;
    for (int o = 16; o > 0; o >>= 1) {
      pn += __shfl_xor(pn, o, 32);
      pd += __shfl_xor(pd, o, 32);
    }
    if (f == 0) { redp[g][0] = pn; redp[g][1] = pd; }
  }
  __syncthreads();
  if (tid == 0) {
    float num = redp[0][0] + redp[1][0] + redp[2][0] + redp[3][0];
    float den = redp[0][1] + redp[1][1] + redp[2][1] + redp[3][1];
    ws_pn[h * 32 + chunk] = num;
    ws_pd[h * 32 + chunk] = den;
  }
}

// ---------------------------------------------------------------------------
// C: conv. grid (b, h) = 128 blocks, 512 threads, 1 barrier on the fast path.
// flag==0: sn from S's partials. flag==1: full in-block pi fallback (R14).
// ---------------------------------------------------------------------------
__global__ __launch_bounds__(512, 1)
void conv_kernel(const float* __restrict__ x, const float* __restrict__ weight,
                 const float* __restrict__ bias, const float* __restrict__ ws_ta,
                 const float* __restrict__ ws_rs, const float* __restrict__ ws_fa,
                 const float* __restrict__ ws_rsF, const float* __restrict__ ws_pn,
                 const float* __restrict__ ws_pd, float* __restrict__ out) {
  const int b = blockIdx.x, h = blockIdx.y;
  const int tid = (int)threadIdx.x;
  const int lane = tid & 63, wvi = tid >> 6;

  __shared__ __align__(16) float faS[Fc * WS36];   // fa[f2][f] row-major
  __shared__ __align__(16) float faTS[Fc * WS36];  // faT (fallback)
  __shared__ __align__(16) float W0s[Fc * HDc];
  __shared__ __align__(16) float W1s[Fc * HDc];
  __shared__ __align__(16) float wbuf[Tc * WS36];  // fallback rows
  __shared__ __align__(16) float vtmp[Nc];         // fallback PRNG
  __shared__ float rsT[Tc], rsF[Fc];
  __shared__ float pnL[32], pdL[32];
  __shared__ float red[8][2];
  __shared__ int flagS;

  const int t = tid >> 2, fq = tid & 3, f0 = 8 * fq;

  if (tid < Tc) rsT[tid] = ws_rs[h * Tc + tid];
  if (tid < Fc) rsF[tid] = ws_rsF[h * Fc + tid];
  {
    W0s[tid] = weight[h * (Fc * HDc) + tid];
    W1s[tid] = weight[(Hc + h) * (Fc * HDc) + tid];
  }
  for (int i = tid; i < Fc * Fc; i += 512) {
    float fv = ws_fa[h * (Fc * Fc) + i];
    faS[(i >> 5) * WS36 + (i & 31)] = fv;
    faTS[(i & 31) * WS36 + (i >> 5)] = fv;
  }
  if (tid < 32) { pnL[tid] = ws_pn[h * 32 + tid]; pdL[tid] = ws_pd[h * 32 + tid]; }
  if (tid < 64) {
    int nz = (ws_rs[h * Tc + tid] > 0.f) || (ws_rs[h * Tc + tid + 64] > 0.f);
    unsigned long long bal = __ballot(nz);
    if (tid == 0) flagS = (bal != 0ull) ? 1 : 0;
  }
  const float* xb = x + (size_t)b * Nc;
  float4 xva = *(const float4*)&xb[t * Fc + f0];
  float4 xvb = *(const float4*)&xb[t * Fc + f0 + 4];
  __syncthreads();  // single barrier on fast path

  float s_reg[8];
  {
    float rrow = rsT[t];
#pragma unroll
    for (int j = 0; j < 8; ++j)
      s_reg[j] = 1.0f / sqrtf(rrow + rsF[f0 + j] + 1.0f + 1e-10f);
  }

  float sn;
  if (!flagS) {
    float num = 0.f, den = 0.f;
#pragma unroll
    for (int i2 = 0; i2 < 32; ++i2) { num += pnL[i2]; den += pdL[i2]; }
    sn = fmaxf(fabsf(num / den), 1.0f);
  } else {
    // ---------- fallback: full in-block pi with M1 (R14-proven) ----------
    {
      uint32_t fk0 = 0u, fk1 = (uint32_t)h;
      threefry2x32(0u, 42u, fk0, fk1);
      float n0[4], n1[4];
#pragma unroll
      for (int jj = 0; jj < 4; ++jj) {
        int l = tid * 4 + jj;
        uint32_t c0 = (uint32_t)l, c1 = (uint32_t)(l + 2048);
        threefry2x32(fk0, fk1, c0, c1);
        n0[jj] = jax_normal_from_bits(c0);
        n1[jj] = jax_normal_from_bits(c1);
      }
      *(float4*)&vtmp[tid * 4]        = make_float4(n0[0], n0[1], n0[2], n0[3]);
      *(float4*)&vtmp[2048 + tid * 4] = make_float4(n1[0], n1[1], n1[2], n1[3]);
    }
    __syncthreads();
    float v[8];
    {
      float4 v0a = *(const float4*)&vtmp[t * Fc + f0];
      float4 v0b = *(const float4*)&vtmp[t * Fc + f0 + 4];
      v[0]=v0a.x; v[1]=v0a.y; v[2]=v0a.z; v[3]=v0a.w;
      v[4]=v0b.x; v[5]=v0b.y; v[6]=v0b.z; v[7]=v0b.w;
    }
    const int srcBase = lane & 60;
    float u4[8];
    for (int it = 0; it < 4; ++it) {
      float w[8];
#pragma unroll
      for (int j = 0; j < 8; ++j) w[j] = s_reg[j] * v[j];
      *(float4*)&wbuf[t * WS36 + f0]     = make_float4(w[0], w[1], w[2], w[3]);
      *(float4*)&wbuf[t * WS36 + f0 + 4] = make_float4(w[4], w[5], w[6], w[7]);
      __syncthreads();
      float wrow[32];
#pragma unroll
      for (int oq = 0; oq < 4; ++oq)
#pragma unroll
        for (int j = 0; j < 8; ++j)
          wrow[oq * 8 + j] = __shfl(w[j], srcBase + oq, 64);
      float acc[8] = {};
#pragma unroll
      for (int f2 = 0; f2 < Fc; ++f2) {
        float4 fa0 = *(const float4*)&faTS[f2 * WS36 + f0];
        float4 fa1 = *(const float4*)&faTS[f2 * WS36 + f0 + 4];
        float ww = wrow[f2];
        acc[0] += ww * fa0.x; acc[1] += ww * fa0.y;
        acc[2] += ww * fa0.z; acc[3] += ww * fa0.w;
        acc[4] += ww * fa1.x; acc[5] += ww * fa1.y;
        acc[6] += ww * fa1.z; acc[7] += ww * fa1.w;
      }
      {
        const float* taG = ws_ta + (size_t)h * (Tc * Tc) + (size_t)t * Tc;
        for (int k = 0; k < Tc; ++k) {
          float tak = taG[k];
          float4 w0 = *(const float4*)&wbuf[k * WS36 + f0];
          float4 w1 = *(const float4*)&wbuf[k * WS36 + f0 + 4];
          acc[0] += tak * w0.x; acc[1] += tak * w0.y;
          acc[2] += tak * w0.z; acc[3] += tak * w0.w;
          acc[4] += tak * w1.x; acc[5] += tak * w1.y;
          acc[6] += tak * w1.z; acc[7] += tak * w1.w;
        }
      }
      __syncthreads();
      float nv[8];
#pragma unroll
      for (int j = 0; j < 8; ++j) {
        float a = acc[j] + w[j];
        nv[j] = v[j] - s_reg[j] * a;
      }
      if (it < 3) {
#pragma unroll
        for (int j = 0; j < 8; ++j) v[j] = nv[j];
      } else {
#pragma unroll
        for (int j = 0; j < 8; ++j) u4[j] = nv[j];
      }
    }
    float pn = 0.f, pd = 0.f;
#pragma unroll
    for (int j = 0; j < 8; ++j) { pn += v[j] * u4[j]; pd += v[j] * v[j]; }
    for (int o = 32; o > 0; o >>= 1) {
      pn += __shfl_down(pn, o, 64);
      pd += __shfl_down(pd, o, 64);
    }
    if (lane == 0) { red[wvi][0] = pn; red[wvi][1] = pd; }
    __syncthreads();
    float num = 0.f, den = 0.f;
#pragma unroll
    for (int i2 = 0; i2 < 8; ++i2) { num += red[i2][0]; den += red[i2][1]; }
    sn = fmaxf(fabsf(num / den), 1.0f);
  }
  const float csn = 2.0f / sn;
  const float cm1 = csn - 1.0f;

  float X[8] = {xva.x, xva.y, xva.z, xva.w, xvb.x, xvb.y, xvb.z, xvb.w};
  float Z[8];
#pragma unroll
  for (int j = 0; j < 8; ++j) Z[j] = s_reg[j] * X[j];

  float gacc[8] = {};
  if (flagS) {  // rare: G1[t][f] = sum_k ta[k][t] Z[k][f]
    __syncthreads();
    *(float4*)&wbuf[t * WS36 + f0]     = make_float4(Z[0], Z[1], Z[2], Z[3]);
    *(float4*)&wbuf[t * WS36 + f0 + 4] = make_float4(Z[4], Z[5], Z[6], Z[7]);
    __syncthreads();
    const float* taG = ws_ta + (size_t)h * (Tc * Tc);
    for (int k = 0; k < Tc; ++k) {
      float tak = taG[(size_t)k * Tc + t];
      float4 z0 = *(const float4*)&wbuf[k * WS36 + f0];
      float4 z1 = *(const float4*)&wbuf[k * WS36 + f0 + 4];
      gacc[0] += tak * z0.x; gacc[1] += tak * z0.y;
      gacc[2] += tak * z0.z; gacc[3] += tak * z0.w;
      gacc[4] += tak * z1.x; gacc[5] += tak * z1.y;
      gacc[6] += tak * z1.z; gacc[7] += tak * z1.w;
    }
  }
  // Z @ fa
  {
    const int srcBase = lane & 60;
    float zrow[32];
#pragma unroll
    for (int oq = 0; oq < 4; ++oq)
#pragma unroll
      for (int j = 0; j < 8; ++j)
        zrow[oq * 8 + j] = __shfl(Z[j], srcBase + oq, 64);
#pragma unroll
    for (int f2 = 0; f2 < Fc; ++f2) {
      float4 fa0 = *(const float4*)&faS[f2 * WS36 + f0];
      float4 fa1 = *(const float4*)&faS[f2 * WS36 + f0 + 4];
      float zz = zrow[f2];
      gacc[0] += zz * fa0.x; gacc[1] += zz * fa0.y;
      gacc[2] += zz * fa0.z; gacc[3] += zz * fa0.w;
      gacc[4] += zz * fa1.x; gacc[5] += zz * fa1.y;
      gacc[6] += zz * fa1.z; gacc[7] += zz * fa1.w;
    }
  }
  float G[8];
#pragma unroll
  for (int j = 0; j < 8; ++j)
    G[j] = cm1 * X[j] - csn * s_reg[j] * (gacc[j] + Z[j]);

  float acc2[16] = {};
#pragma unroll
  for (int jf = 0; jf < 8; ++jf) {
    int f = f0 + jf;
#pragma unroll
    for (int hq = 0; hq < 4; ++hq) {
      float4 w0 = *(const float4*)&W0s[f * HDc + 4 * hq];
      float4 w1 = *(const float4*)&W1s[f * HDc + 4 * hq];
      acc2[4*hq+0] += X[jf] * w0.x + G[jf] * w1.x;
      acc2[4*hq+1] += X[jf] * w0.y + G[jf] * w1.y;
      acc2[4*hq+2] += X[jf] * w0.z + G[jf] * w1.z;
      acc2[4*hq+3] += X[jf] * w0.w + G[jf] * w1.w;
    }
  }
#pragma unroll
  for (int i2 = 0; i2 < 16; ++i2) {
    acc2[i2] += __shfl_xor(acc2[i2], 1, 64);
    acc2[i2] += __shfl_xor(acc2[i2], 2, 64);
  }
  {
    float4 bv = *(const float4*)&bias[h * HDc + 4 * fq];
    float4 o4;
    if      (fq == 0) o4 = make_float4(acc2[0],  acc2[1],  acc2[2],  acc2[3]);
    else if (fq == 1) o4 = make_float4(acc2[4],  acc2[5],  acc2[6],  acc2[7]);
    else if (fq == 2) o4 = make_float4(acc2[8],  acc2[9],  acc2[10], acc2[11]);
    else              o4 = make_float4(acc2[12], acc2[13], acc2[14], acc2[15]);
    o4.x += bv.x; o4.y += bv.y; o4.z += bv.z; o4.w += bv.w;
    *(float4*)&out[((size_t)b * Tc + t) * (Hc * HDc) + h * HDc + 4 * fq] = o4;
  }
}

extern "C" void kernel_launch(void* const* d_in, const int* in_sizes, int n_in,
                              void* d_out, int out_size, void* d_ws, size_t ws_size,
                              hipStream_t stream) {
  const float* x      = (const float*)d_in[0];
  const float* weight = (const float*)d_in[1];
  const float* bias   = (const float*)d_in[2];
  const float* tqg    = (const float*)d_in[3];
  const float* tkg    = (const float*)d_in[4];
  const float* ffg    = (const float*)d_in[5];
  float* out = (float*)d_out;

  float* ws = (float*)d_ws;
  float* ws_ta  = ws;             // 65536
  float* ws_rs  = ws + 65536;     // 512
  float* ws_q   = ws + 66048;     // 16384
  float* ws_k   = ws + 82432;     // 16384
  float* ws_fa  = ws + 98816;     // 4096
  float* ws_rsF = ws + 102912;    // 128
  float* ws_pn  = ws + 103040;    // 128
  float* ws_pd  = ws + 103168;    // 128

  proj_kernel<<<dim3(Bc), dim3(512), 0, stream>>>(
      x, weight, tqg, tkg, ffg, ws_q, ws_k, ws_fa, ws_rsF);
  score_kernel<<<dim3(Hc, 32), dim3(256), 0, stream>>>(
      ws_q, ws_k, ws_fa, ws_rsF, ws_ta, ws_rs, ws_pn, ws_pd);
  conv_kernel<<<dim3(Bc, Hc), dim3(512), 0, stream>>>(
      x, weight, bias, ws_ta, ws_rs, ws_fa, ws_rsF, ws_pn, ws_pd, out);
}